// Round 1
// baseline (6260.761 us; speedup 1.0000x reference)
//
#include <hip/hip_runtime.h>
#include <cstdint>
#include <cstddef>

#define Hh 64
#define Vv 32000
#define Bb 32
#define Tt 512
#define GPW 8            // workgroups per batch chain
#define NBLK (Bb*GPW)    // 256

// ---- workspace layout (bytes) ----
#define RING_OFF   0u
#define RING_SZ    ((unsigned)(Bb*2*Hh*Hh*4))          // 1,048,576  U ring, depth 2
#define SMAX_OFF   (RING_OFF + RING_SZ)
#define SMAX_SZ    ((unsigned)(Bb*2*GPW*4))            // slice maxes
#define FLAG_OFF   (SMAX_OFF + SMAX_SZ)
#define FLAG_SZ    ((unsigned)(Bb*GPW*64))             // 64B-padded seqnum flags
#define IPBUF_OFF  (FLAG_OFF + FLAG_SZ)
#define IPBUF_SZ   ((unsigned)(Bb*Tt*Hh*4))            // emission log-probs ip[b][t][j]
#define DMAX_OFF   (IPBUF_OFF + IPBUF_SZ)
#define DMAX_SZ    ((unsigned)(Bb*Tt*4))               // per-(b,t) max_j ip
#define SF_OFF     (DMAX_OFF + DMAX_SZ)                // Sfinal[b]

__device__ __forceinline__ float wave_max(float v){
  #pragma unroll
  for (int off=32; off; off>>=1) v = fmaxf(v, __shfl_xor(v, off, 64));
  return v;
}

__global__ __launch_bounds__(512) void sohmm_scan(
    const float* __restrict__ alpha, const float* __restrict__ beta,
    const int* __restrict__ ids, float* __restrict__ out,
    float* __restrict__ ring, float* __restrict__ smax,
    unsigned int* __restrict__ flags, float* __restrict__ ipbuf,
    float* __restrict__ dmax, float* __restrict__ Sfinal)
{
  const int blk  = blockIdx.x;
  const int b    = blk & 31;   // group members b, b+32, ... share XCD (perf heuristic only)
  const int g    = blk >> 5;   // i-slice index 0..7
  const int tid  = threadIdx.x;
  const int il   = tid & 7;
  const int j    = tid >> 3;   // 0..63
  const int i    = g*8 + il;   // global i
  const int w    = tid >> 6;   // wave 0..7
  const int lane = tid & 63;

  __shared__ float Z[Hh][72];   // padded: stride 72 f32 = 288B (16B aligned, conflict-light)
  __shared__ float wred[8];
  __shared__ float smaxbuf[GPW];

  // ---- persistent alpha slice row -> registers (64 VGPRs) ----
  float a[64];
  {
    const float4* ap = (const float4*)(alpha + ((size_t)i*Hh + j)*Hh);
    #pragma unroll
    for (int k4=0;k4<16;k4++){
      float4 v = ap[k4];
      a[4*k4+0]=v.x; a[4*k4+1]=v.y; a[4*k4+2]=v.z; a[4*k4+3]=v.w;
    }
  }

  // ---- phase A: precompute emissions ip[b][t][j] and dmax[b][t] for t in [g*64, g*64+64) ----
  for (int r=0;r<8;r++){
    int t  = g*64 + r*8 + w;                 // one t per wave-iteration
    int id = ids[b*Tt + t];
    float ip = beta[(size_t)lane*Vv + id];   // lane == j here
    float m  = wave_max(ip);
    __hip_atomic_store(&ipbuf[((size_t)b*Tt + t)*Hh + lane], ip,
                       __ATOMIC_RELAXED, __HIP_MEMORY_SCOPE_AGENT);
    if (lane==0)
      __hip_atomic_store(&dmax[b*Tt + t], m,
                         __ATOMIC_RELAXED, __HIP_MEMORY_SCOPE_AGENT);
  }
  __syncthreads();
  if (tid==0)
    __hip_atomic_store(&flags[(b*GPW+g)*16], 1u,
                       __ATOMIC_RELEASE, __HIP_MEMORY_SCOPE_AGENT);
  if (tid < GPW){
    while (__hip_atomic_load(&flags[(b*GPW+tid)*16],
                             __ATOMIC_ACQUIRE, __HIP_MEMORY_SCOPE_AGENT) < 1u)
      __builtin_amdgcn_s_sleep(1);
  }
  __syncthreads();

  // ---- step 0: y0 = ip[T-1][j]; U0 = exp(ip - delta0) ----
  float S = dmax[b*Tt + (Tt-1)];            // S_0 = delta_0 (write-once data, now visible)
  {
    float ip = ipbuf[((size_t)b*Tt + (Tt-1))*Hh + j];
    float u  = __expf(ip - S);
    __hip_atomic_store(&ring[((size_t)b*2+0)*4096 + i*Hh + j], u,
                       __ATOMIC_RELAXED, __HIP_MEMORY_SCOPE_AGENT);
    out[(((size_t)0*Hh + i)*Hh + j)*Bb + b] = ip;   // y0 exactly
    float m = wave_max(u);
    if (lane==0) wred[w]=m;
    __syncthreads();
    if (tid==0){
      float mm = wred[0];
      #pragma unroll
      for (int q=1;q<8;q++) mm = fmaxf(mm, wred[q]);
      __hip_atomic_store(&smax[((size_t)b*2+0)*GPW + g], mm,
                         __ATOMIC_RELAXED, __HIP_MEMORY_SCOPE_AGENT);
    }
    __syncthreads();
    if (tid==0)
      __hip_atomic_store(&flags[(b*GPW+g)*16], 2u,
                         __ATOMIC_RELEASE, __HIP_MEMORY_SCOPE_AGENT);
  }

  // ---- steps 1..T-1 ----
  for (int s=1; s<Tt; s++){
    const int slot = s & 1, pslot = slot ^ 1;
    const int t = (Tt-1) - s;

    // wait for all slices of step s-1; fetch their maxes
    if (tid < GPW){
      while (__hip_atomic_load(&flags[(b*GPW+tid)*16],
                               __ATOMIC_ACQUIRE, __HIP_MEMORY_SCOPE_AGENT) < (unsigned)(s+1))
        __builtin_amdgcn_s_sleep(1);
      smaxbuf[tid] = __hip_atomic_load(&smax[((size_t)b*2+pslot)*GPW + tid],
                                       __ATOMIC_RELAXED, __HIP_MEMORY_SCOPE_AGENT);
    }
    __syncthreads();

    float mu = smaxbuf[0];
    #pragma unroll
    for (int q=1;q<GPW;q++) mu = fmaxf(mu, smaxbuf[q]);
    const float rinv = 1.0f / mu;

    float ipv = ipbuf[((size_t)b*Tt + t)*Hh + j];   // cached (write-once)
    float dmv = dmax[b*Tt + t];
    float e   = __expf(ipv - dmv);
    S = S + __logf(mu) + dmv;                        // S_s = m_{s-1} + delta_s

    // fill Z (normalized previous U) into LDS: 4096 f32, coherent scalar loads
    const float* rp = &ring[((size_t)b*2+pslot)*4096];
    #pragma unroll
    for (int q=0;q<8;q++){
      int f = q*512 + tid;
      float v = __hip_atomic_load(&rp[f], __ATOMIC_RELAXED, __HIP_MEMORY_SCOPE_AGENT);
      Z[f>>6][f&63] = v * rinv;
    }
    __syncthreads();

    // U[i][j] = (sum_k a[k] * Z[j][k]) * e    (8 lanes broadcast-share row j)
    float acc = 0.f;
    #pragma unroll
    for (int k4=0;k4<16;k4++){
      float4 z = *(const float4*)(&Z[j][k4*4]);
      acc = fmaf(a[4*k4+0], z.x, acc);
      acc = fmaf(a[4*k4+1], z.y, acc);
      acc = fmaf(a[4*k4+2], z.z, acc);
      acc = fmaf(a[4*k4+3], z.w, acc);
    }
    float u = acc * e;

    out[(((size_t)s*Hh + i)*Hh + j)*Bb + b] = __logf(u) + S;
    __hip_atomic_store(&ring[((size_t)b*2+slot)*4096 + i*Hh + j], u,
                       __ATOMIC_RELAXED, __HIP_MEMORY_SCOPE_AGENT);

    float m = wave_max(u);
    if (lane==0) wred[w]=m;
    __syncthreads();
    if (tid==0){
      float mm = wred[0];
      #pragma unroll
      for (int q=1;q<8;q++) mm = fmaxf(mm, wred[q]);
      __hip_atomic_store(&smax[((size_t)b*2+slot)*GPW + g], mm,
                         __ATOMIC_RELAXED, __HIP_MEMORY_SCOPE_AGENT);
    }
    __syncthreads();
    if (tid==0)
      __hip_atomic_store(&flags[(b*GPW+g)*16], (unsigned)(s+2),
                         __ATOMIC_RELEASE, __HIP_MEMORY_SCOPE_AGENT);
  }

  if (g==0 && tid==0) Sfinal[b] = S;   // plain store; kernel boundary synchronizes
}

__global__ __launch_bounds__(256) void sohmm_final(
    const float* __restrict__ gamma, const float* __restrict__ ring,
    const float* __restrict__ Sfinal, float* __restrict__ out)
{
  const int b = blockIdx.x, tid = threadIdx.x;
  const int w = tid>>6, lane = tid&63;
  __shared__ float red[4], red2[4];

  float gm = -3.4e38f;
  #pragma unroll
  for (int q=0;q<16;q++) gm = fmaxf(gm, gamma[q*256+tid]);
  gm = wave_max(gm);
  if (lane==0) red[w] = gm;
  __syncthreads();
  gm = fmaxf(fmaxf(red[0],red[1]), fmaxf(red[2],red[3]));
  __syncthreads();

  const float* W = ring + ((size_t)b*2 + ((Tt-1)&1))*4096;   // slot 1 holds U_{T-1}
  float se=0.f, dot=0.f;
  #pragma unroll
  for (int q=0;q<16;q++){
    int idx = q*256+tid;
    float gq = __expf(gamma[idx]-gm);
    se  += gq;
    dot += gq * W[idx];
  }
  #pragma unroll
  for (int off=32; off; off>>=1){
    se  += __shfl_xor(se,  off, 64);
    dot += __shfl_xor(dot, off, 64);
  }
  if (lane==0){ red[w]=se; red2[w]=dot; }
  __syncthreads();
  if (tid==0){
    float ses  = red[0]+red[1]+red[2]+red[3];
    float dots = red2[0]+red2[1]+red2[2]+red2[3];
    out[(size_t)Tt*Hh*Hh*Bb + b] = __logf(dots/ses) + Sfinal[b];
  }
}

extern "C" void kernel_launch(void* const* d_in, const int* in_sizes, int n_in,
                              void* d_out, int out_size, void* d_ws, size_t ws_size,
                              hipStream_t stream)
{
  (void)in_sizes; (void)n_in; (void)out_size; (void)ws_size;
  const float* alpha = (const float*)d_in[0];
  const float* beta  = (const float*)d_in[1];
  const float* gamma = (const float*)d_in[2];
  const int*   ids   = (const int*)d_in[3];
  float* out = (float*)d_out;
  char*  ws  = (char*)d_ws;

  float*        ring  = (float*)(ws + RING_OFF);
  float*        smax  = (float*)(ws + SMAX_OFF);
  unsigned int* flags = (unsigned int*)(ws + FLAG_OFF);
  float*        ipbuf = (float*)(ws + IPBUF_OFF);
  float*        dmaxp = (float*)(ws + DMAX_OFF);
  float*        sfin  = (float*)(ws + SF_OFF);

  hipMemsetAsync(flags, 0, FLAG_SZ, stream);
  hipLaunchKernelGGL(sohmm_scan, dim3(NBLK), dim3(512), 0, stream,
                     alpha, beta, ids, out, ring, smax, flags, ipbuf, dmaxp, sfin);
  hipLaunchKernelGGL(sohmm_final, dim3(Bb), dim3(256), 0, stream,
                     gamma, ring, sfin, out);
}

// Round 2
// 5820.336 us; speedup vs baseline: 1.0757x; 1.0757x over previous
//
#include <hip/hip_runtime.h>
#include <cstdint>
#include <cstddef>

#define Hh 64
#define Vv 32000
#define Bb 32
#define Tt 512
#define GPW 8            // workgroups per batch chain
#define NBLK (Bb*GPW)    // 256

// ---- workspace layout (bytes) ----
#define RING_OFF   0u
#define RING_SZ    ((unsigned)(Bb*2*Hh*Hh*4))          // 1 MB  U ring, depth 2
#define FLAG_OFF   (RING_OFF + RING_SZ)
#define FLAG_SZ    ((unsigned)(Bb*2*GPW*8))            // u64 flags[b][slot][g] (seq<<32 | smax bits)
#define IPBUF_OFF  (FLAG_OFF + 4096u)
#define IPBUF_SZ   ((unsigned)(Bb*Tt*Hh*4))            // emission log-probs ip[b][t][j]
#define DMAX_OFF   (IPBUF_OFF + IPBUF_SZ)
#define DMAX_SZ    ((unsigned)(Bb*Tt*4))               // per-(b,t) max_j ip
#define SF_OFF     (DMAX_OFF + DMAX_SZ)                // Sfinal[b]

__device__ __forceinline__ float wave_max(float v){
  #pragma unroll
  for (int off=32; off; off>>=1) v = fmaxf(v, __shfl_xor(v, off, 64));
  return v;
}

__global__ __launch_bounds__(512) void sohmm_scan(
    const float* __restrict__ alpha, const float* __restrict__ beta,
    const int* __restrict__ ids, float* __restrict__ out,
    float* __restrict__ ring, unsigned long long* __restrict__ flags,
    float* __restrict__ ipbuf, float* __restrict__ dmax,
    float* __restrict__ Sfinal)
{
  const int blk  = blockIdx.x;
  const int b    = blk & 31;   // group members b, b+32, ... share XCD (perf heuristic only)
  const int g    = blk >> 5;   // i-slice index 0..7
  const int tid  = threadIdx.x;
  const int il   = tid & 7;
  const int j    = tid >> 3;   // 0..63
  const int i    = g*8 + il;   // global i
  const int w    = tid >> 6;   // wave 0..7
  const int lane = tid & 63;

  __shared__ float Z[Hh][72];   // padded stride 72 f32: compute reads are 2-way (free)
  __shared__ float wred[8];
  __shared__ float smaxbuf[GPW];

  unsigned long long* myflags = &flags[(size_t)b*2*GPW];   // [slot][g]

  // ---- persistent alpha slice row -> registers (64 VGPRs) ----
  float a[64];
  {
    const float4* ap = (const float4*)(alpha + ((size_t)i*Hh + j)*Hh);
    #pragma unroll
    for (int k4=0;k4<16;k4++){
      float4 v = ap[k4];
      a[4*k4+0]=v.x; a[4*k4+1]=v.y; a[4*k4+2]=v.z; a[4*k4+3]=v.w;
    }
  }

  // ---- phase A: emissions ip[b][t][j], dmax[b][t] for t in [g*64, g*64+64) ----
  for (int r=0;r<8;r++){
    int t  = g*64 + r*8 + w;
    int id = ids[b*Tt + t];
    float ip = beta[(size_t)lane*Vv + id];   // lane == j here
    float m  = wave_max(ip);
    __hip_atomic_store(&ipbuf[((size_t)b*Tt + t)*Hh + lane], ip,
                       __ATOMIC_RELAXED, __HIP_MEMORY_SCOPE_AGENT);
    if (lane==0)
      __hip_atomic_store(&dmax[b*Tt + t], m,
                         __ATOMIC_RELAXED, __HIP_MEMORY_SCOPE_AGENT);
  }
  __syncthreads();
  if (tid==0)
    __hip_atomic_store(&myflags[1*GPW + g], (unsigned long long)1<<32,
                       __ATOMIC_RELEASE, __HIP_MEMORY_SCOPE_AGENT);
  if (tid < GPW){
    while ((__hip_atomic_load(&myflags[1*GPW + tid],
                              __ATOMIC_ACQUIRE, __HIP_MEMORY_SCOPE_AGENT) >> 32) < 1ull)
      __builtin_amdgcn_s_sleep(1);
  }
  __syncthreads();

  // ---- step 0: y0 = ip[T-1][j]; U0 = exp(ip - delta0); ring pos = g*512 + tid ----
  float S = __hip_atomic_load(&dmax[b*Tt + (Tt-1)], __ATOMIC_RELAXED, __HIP_MEMORY_SCOPE_AGENT);
  {
    float ip = __hip_atomic_load(&ipbuf[((size_t)b*Tt + (Tt-1))*Hh + j],
                                 __ATOMIC_RELAXED, __HIP_MEMORY_SCOPE_AGENT);
    float u  = __expf(ip - S);
    __hip_atomic_store(&ring[((size_t)b*2+0)*4096 + g*512 + tid], u,
                       __ATOMIC_RELAXED, __HIP_MEMORY_SCOPE_AGENT);
    float m = wave_max(u);
    if (lane==0) wred[w]=m;
    __syncthreads();
    if (tid==0){
      float mm = wred[0];
      #pragma unroll
      for (int q=1;q<8;q++) mm = fmaxf(mm, wred[q]);
      unsigned long long pk = ((unsigned long long)2<<32) | (unsigned long long)__float_as_uint(mm);
      __hip_atomic_store(&myflags[0*GPW + g], pk,
                         __ATOMIC_RELEASE, __HIP_MEMORY_SCOPE_AGENT);
    }
    out[(((size_t)0*Hh + i)*Hh + j)*Bb + b] = ip;   // after release: drains lazily
  }

  // ---- steps 1..T-1 ----
  for (int s=1; s<Tt; s++){
    const int slot = s & 1, pslot = slot ^ 1;
    const int t = (Tt-1) - s;

    // wait for all slices of step s-1 (flag carries packed smax)
    if (tid < GPW){
      unsigned long long v;
      while (((v = __hip_atomic_load(&myflags[pslot*GPW + tid],
                                     __ATOMIC_ACQUIRE, __HIP_MEMORY_SCOPE_AGENT)) >> 32)
             < (unsigned long long)(s+1))
        __builtin_amdgcn_s_sleep(1);
      smaxbuf[tid] = __uint_as_float((unsigned)v);
    }
    __syncthreads();

    float mu = smaxbuf[0];
    #pragma unroll
    for (int q=1;q<GPW;q++) mu = fmaxf(mu, smaxbuf[q]);
    const float rinv = 1.0f / mu;

    float ipv = __hip_atomic_load(&ipbuf[((size_t)b*Tt + t)*Hh + j],
                                  __ATOMIC_RELAXED, __HIP_MEMORY_SCOPE_AGENT);
    float dmv = __hip_atomic_load(&dmax[b*Tt + t],
                                  __ATOMIC_RELAXED, __HIP_MEMORY_SCOPE_AGENT);
    float e   = __expf(ipv - dmv);
    S = S + __logf(mu) + dmv;                        // S_s = m_{s-1} + delta_s

    // fill Z from ring (coalesced reads; positions encode j*8+il within each 512-block)
    const float* rp = &ring[((size_t)b*2+pslot)*4096];
    #pragma unroll
    for (int q=0;q<8;q++){
      int p = q*512 + tid;
      float v = __hip_atomic_load(&rp[p], __ATOMIC_RELAXED, __HIP_MEMORY_SCOPE_AGENT);
      int r = q*8 + (tid & 7);       // semantic row i'
      int c = tid >> 3;              // semantic col j'
      Z[r][c] = v * rinv;            // LDS scatter: exactly 2-way (free)
    }
    __syncthreads();

    // U[i][j] = (sum_k a[k] * Z[j][k]) * e    (8 lanes broadcast-share row j)
    float acc = 0.f;
    #pragma unroll
    for (int k4=0;k4<16;k4++){
      float4 z = *(const float4*)(&Z[j][k4*4]);
      acc = fmaf(a[4*k4+0], z.x, acc);
      acc = fmaf(a[4*k4+1], z.y, acc);
      acc = fmaf(a[4*k4+2], z.z, acc);
      acc = fmaf(a[4*k4+3], z.w, acc);
    }
    float u = acc * e;

    float m = wave_max(u);
    if (lane==0) wred[w]=m;

    // coalesced ring store (wave writes 256B contiguous)
    __hip_atomic_store(&ring[((size_t)b*2+slot)*4096 + g*512 + tid], u,
                       __ATOMIC_RELAXED, __HIP_MEMORY_SCOPE_AGENT);
    __syncthreads();
    if (tid==0){
      float mm = wred[0];
      #pragma unroll
      for (int q=1;q<8;q++) mm = fmaxf(mm, wred[q]);
      unsigned long long pk = ((unsigned long long)(s+2)<<32) | (unsigned long long)__float_as_uint(mm);
      __hip_atomic_store(&myflags[slot*GPW + g], pk,
                         __ATOMIC_RELEASE, __HIP_MEMORY_SCOPE_AGENT);
    }

    // scattered out store AFTER the release: drains under next step's poll
    out[(((size_t)s*Hh + i)*Hh + j)*Bb + b] = __logf(u) + S;
  }

  if (g==0 && tid==0) Sfinal[b] = S;   // kernel boundary synchronizes
}

__global__ __launch_bounds__(256) void sohmm_final(
    const float* __restrict__ gamma, const float* __restrict__ ring,
    const float* __restrict__ Sfinal, float* __restrict__ out)
{
  const int b = blockIdx.x, tid = threadIdx.x;
  const int w = tid>>6, lane = tid&63;
  __shared__ float red[4], red2[4];

  float gm = -3.4e38f;
  #pragma unroll
  for (int q=0;q<16;q++) gm = fmaxf(gm, gamma[q*256+tid]);
  gm = wave_max(gm);
  if (lane==0) red[w] = gm;
  __syncthreads();
  gm = fmaxf(fmaxf(red[0],red[1]), fmaxf(red[2],red[3]));
  __syncthreads();

  const float* W = ring + ((size_t)b*2 + ((Tt-1)&1))*4096;   // slot 1 holds U_{T-1}
  float se=0.f, dot=0.f;
  #pragma unroll
  for (int q=0;q<16;q++){
    int idx = q*256+tid;           // semantic i*64+j
    int ii = idx>>6, jj = idx&63;
    int p  = (ii>>3)*512 + jj*8 + (ii&7);   // ring position encoding
    float gq = __expf(gamma[idx]-gm);
    se  += gq;
    dot += gq * W[p];
  }
  #pragma unroll
  for (int off=32; off; off>>=1){
    se  += __shfl_xor(se,  off, 64);
    dot += __shfl_xor(dot, off, 64);
  }
  if (lane==0){ red[w]=se; red2[w]=dot; }
  __syncthreads();
  if (tid==0){
    float ses  = red[0]+red[1]+red[2]+red[3];
    float dots = red2[0]+red2[1]+red2[2]+red2[3];
    out[(size_t)Tt*Hh*Hh*Bb + b] = __logf(dots/ses) + Sfinal[b];
  }
}

extern "C" void kernel_launch(void* const* d_in, const int* in_sizes, int n_in,
                              void* d_out, int out_size, void* d_ws, size_t ws_size,
                              hipStream_t stream)
{
  (void)in_sizes; (void)n_in; (void)out_size; (void)ws_size;
  const float* alpha = (const float*)d_in[0];
  const float* beta  = (const float*)d_in[1];
  const float* gamma = (const float*)d_in[2];
  const int*   ids   = (const int*)d_in[3];
  float* out = (float*)d_out;
  char*  ws  = (char*)d_ws;

  float*              ring  = (float*)(ws + RING_OFF);
  unsigned long long* flags = (unsigned long long*)(ws + FLAG_OFF);
  float*              ipbuf = (float*)(ws + IPBUF_OFF);
  float*              dmaxp = (float*)(ws + DMAX_OFF);
  float*              sfin  = (float*)(ws + SF_OFF);

  hipMemsetAsync(flags, 0, FLAG_SZ, stream);
  hipLaunchKernelGGL(sohmm_scan, dim3(NBLK), dim3(512), 0, stream,
                     alpha, beta, ids, out, ring, flags, ipbuf, dmaxp, sfin);
  hipLaunchKernelGGL(sohmm_final, dim3(Bb), dim3(256), 0, stream,
                     gamma, ring, sfin, out);
}